// Round 2
// baseline (1694.936 us; speedup 1.0000x reference)
//
#include <hip/hip_runtime.h>
#include <hip/hip_bf16.h>

// ---------------- problem constants ----------------
#define FIN 165
#define HID 128
#define BM 64          // gemm row tile
#define BN 128         // gemm col tile (== HID)
#define KT 32          // gemm k tile
#define XPAD 68        // padded row length for transposed x tile (16B-aligned rows)
#define SCHUNK 2048    // scan chunk (256 thr * 8)

// ---------------- CSR build ----------------
__global__ __launch_bounds__(256) void count_deg(const int* __restrict__ dst,
                                                 int* __restrict__ deg, int E, int n) {
    int e = blockIdx.x * 256 + threadIdx.x;
    if (e < E) {
        int d = dst[e];
        if ((unsigned)d < (unsigned)n) atomicAdd(&deg[d], 1);
    }
}

__global__ __launch_bounds__(256) void dinv_k(const int* __restrict__ deg,
                                              float* __restrict__ dinv, int n) {
    int i = blockIdx.x * 256 + threadIdx.x;
    if (i < n) dinv[i] = rsqrtf((float)(deg[i] + 1));   // +1 self loop
}

__global__ __launch_bounds__(256) void scan_partial(const int* __restrict__ deg,
                                                    int* __restrict__ partial, int n) {
    __shared__ int sm[256];
    int base = blockIdx.x * SCHUNK;
    int s = 0;
    for (int i = threadIdx.x; i < SCHUNK; i += 256) {
        int idx = base + i;
        s += (idx < n) ? deg[idx] : 0;
    }
    sm[threadIdx.x] = s;
    __syncthreads();
    for (int off = 128; off > 0; off >>= 1) {
        if (threadIdx.x < off) sm[threadIdx.x] += sm[threadIdx.x + off];
        __syncthreads();
    }
    if (threadIdx.x == 0) partial[blockIdx.x] = sm[0];
}

// single block, 256 threads; nb <= 256 (200000/2048 = 98)
__global__ __launch_bounds__(256) void scan_level2(int* __restrict__ partial, int nb,
                                                   int* __restrict__ rowptr, int n) {
    __shared__ int sm[256];
    int t = threadIdx.x;
    int v = (t < nb) ? partial[t] : 0;
    sm[t] = v;
    __syncthreads();
    for (int off = 1; off < 256; off <<= 1) {
        int u = (t >= off) ? sm[t - off] : 0;
        __syncthreads();
        sm[t] += u;
        __syncthreads();
    }
    if (t < nb) partial[t] = sm[t] - v;      // exclusive
    if (t == 0) rowptr[n] = sm[255];         // total == E
}

__global__ __launch_bounds__(256) void scan_write(const int* __restrict__ deg,
                                                  const int* __restrict__ partial,
                                                  int* __restrict__ rowptr, int n) {
    __shared__ int sm[256];
    int base = blockIdx.x * SCHUNK;
    int vals[8];
    int s = 0;
#pragma unroll
    for (int q = 0; q < 8; ++q) {
        int idx = base + threadIdx.x * 8 + q;
        vals[q] = (idx < n) ? deg[idx] : 0;
        s += vals[q];
    }
    sm[threadIdx.x] = s;
    __syncthreads();
    for (int off = 1; off < 256; off <<= 1) {
        int u = (threadIdx.x >= off) ? sm[threadIdx.x - off] : 0;
        __syncthreads();
        sm[threadIdx.x] += u;
        __syncthreads();
    }
    int excl = partial[blockIdx.x] + (threadIdx.x > 0 ? sm[threadIdx.x - 1] : 0);
#pragma unroll
    for (int q = 0; q < 8; ++q) {
        int idx = base + threadIdx.x * 8 + q;
        if (idx < n) rowptr[idx] = excl;
        excl += vals[q];
    }
}

// fillptr[i] = rowptr[i]  (cursor copy so fill_csr needs no extra rowptr read)
__global__ __launch_bounds__(256) void copy_cursor(const int* __restrict__ rowptr,
                                                   int* __restrict__ fillptr, int n) {
    int i = blockIdx.x * 256 + threadIdx.x;
    if (i < n) fillptr[i] = rowptr[i];
}

__global__ __launch_bounds__(256) void fill_csr(const int* __restrict__ src,
                                                const int* __restrict__ dst,
                                                int* __restrict__ fillptr,
                                                int* __restrict__ col, int E, int n) {
    int e = blockIdx.x * 256 + threadIdx.x;
    if (e < E) {
        int d = dst[e];
        int s = src[e];
        if ((unsigned)d < (unsigned)n && (unsigned)s < (unsigned)n) {
            int pos = atomicAdd(&fillptr[d], 1);
            col[pos] = s;
        }
    }
}

// ---------------- GEMM: H[r,c] = dinv[r] * sum_k X[r,k] W[k,c] ----------------
// X: [n x K] row major, W: [K x 128], H: [n x 128]
// 256 threads, BM=64 x BN=128 tile, KT=32; thread computes 8 rows x 4 cols.
// Inner loop: 2x ds_read_b128 (xv) + 1x ds_read_b128 (wv) per 32 FMAs -> FMA-bound.
__global__ __launch_bounds__(256) void gemm_scale(const float* __restrict__ X,
                                                  const float* __restrict__ W,
                                                  const float* __restrict__ dinv,
                                                  float* __restrict__ H,
                                                  int n, int K) {
    __shared__ float xs[KT][XPAD];   // transposed x tile, padded (rows 16B-aligned)
    __shared__ float wsm[KT][BN];
    int r0 = blockIdx.x * BM;
    int tid = threadIdx.x;
    int tr = (tid & 7) * 8;          // 8 consecutive rows per thread
    int tc = (tid >> 3) * 4;         // 4 consecutive cols per thread
    float acc[8][4] = {};

    for (int kt = 0; kt < K; kt += KT) {
        // load X tile (64 rows x 32 k), transposed into xs[k][r]
#pragma unroll
        for (int q = 0; q < 8; ++q) {
            int i = tid + q * 256;           // i in [0, 2048)
            int r = i >> 5;                  // row 0..63
            int k = i & 31;                  // k   0..31
            int gr = r0 + r, gk = kt + k;
            float v = 0.f;
            if (gr < n && gk < K) v = X[(long)gr * K + gk];
            xs[k][r] = v;
        }
        // load W tile (32 k x 128 c), no transpose
#pragma unroll
        for (int q = 0; q < 16; ++q) {
            int i = tid + q * 256;           // i in [0, 4096)
            int k = i >> 7;
            int c = i & 127;
            int gk = kt + k;
            wsm[k][c] = (gk < K) ? W[gk * BN + c] : 0.f;
        }
        __syncthreads();
#pragma unroll
        for (int k = 0; k < KT; ++k) {
            float4 xv0 = *(const float4*)&xs[k][tr];
            float4 xv1 = *(const float4*)&xs[k][tr + 4];
            float4 wv  = *(const float4*)&wsm[k][tc];
            float xr[8] = {xv0.x, xv0.y, xv0.z, xv0.w, xv1.x, xv1.y, xv1.z, xv1.w};
            float wc[4] = {wv.x, wv.y, wv.z, wv.w};
#pragma unroll
            for (int r = 0; r < 8; ++r)
#pragma unroll
                for (int c = 0; c < 4; ++c)
                    acc[r][c] += xr[r] * wc[c];
        }
        __syncthreads();
    }
#pragma unroll
    for (int r = 0; r < 8; ++r) {
        int gr = r0 + tr + r;
        if (gr >= n) continue;
        float s = dinv[gr];
        float4 o;
        o.x = acc[r][0] * s; o.y = acc[r][1] * s;
        o.z = acc[r][2] * s; o.w = acc[r][3] * s;
        *(float4*)&H[(long)gr * BN + tc] = o;
    }
}

// ---------------- aggregation: one wave per node, float2 per lane ----------------
// Y[i,f] = relu(dinv[i]*(HS[i,f] + sum_nbr HS[s,f]) + b[f])
__global__ __launch_bounds__(256) void agg_relu(const float* __restrict__ HS,
                                                const int* __restrict__ rowptr,
                                                const int* __restrict__ col,
                                                const float* __restrict__ dinv,
                                                const float* __restrict__ bias,
                                                float* __restrict__ Y, int n) {
    int node = blockIdx.x * 4 + (threadIdx.x >> 6);
    int lane = threadIdx.x & 63;
    if (node >= n) return;
    int start = rowptr[node], end = rowptr[node + 1];
    float2 acc = *(const float2*)&HS[(long)node * HID + 2 * lane];   // self loop
    for (int j0 = start; j0 < end; j0 += 64) {
        int cnt = min(64, end - j0);
        int cv = (j0 + lane < end) ? col[j0 + lane] : 0;
        for (int t = 0; t < cnt; ++t) {
            int c = __shfl(cv, t);
            float2 v = *(const float2*)&HS[(long)c * HID + 2 * lane];
            acc.x += v.x; acc.y += v.y;
        }
    }
    float s = dinv[node];
    float2 b = *(const float2*)&bias[2 * lane];
    float2 o;
    o.x = fmaxf(acc.x * s + b.x, 0.f);
    o.y = fmaxf(acc.y * s + b.y, 0.f);
    *(float2*)&Y[(long)node * HID + 2 * lane] = o;
}

// ---------------- fused layer-2 aggregation + relu + head ----------------
// out[i,:2] = relu(dinv[i]*(HS[i]+sum HS[s]) + b2) @ Wl + bl
__global__ __launch_bounds__(256) void agg_relu_head(const float* __restrict__ HS,
                                                     const int* __restrict__ rowptr,
                                                     const int* __restrict__ col,
                                                     const float* __restrict__ dinv,
                                                     const float* __restrict__ bias,
                                                     const float* __restrict__ Wl,
                                                     const float* __restrict__ bl,
                                                     float* __restrict__ out, int n) {
    int node = blockIdx.x * 4 + (threadIdx.x >> 6);
    int lane = threadIdx.x & 63;
    if (node >= n) return;
    int start = rowptr[node], end = rowptr[node + 1];
    float2 acc = *(const float2*)&HS[(long)node * HID + 2 * lane];   // self loop
    for (int j0 = start; j0 < end; j0 += 64) {
        int cnt = min(64, end - j0);
        int cv = (j0 + lane < end) ? col[j0 + lane] : 0;
        for (int t = 0; t < cnt; ++t) {
            int c = __shfl(cv, t);
            float2 v = *(const float2*)&HS[(long)c * HID + 2 * lane];
            acc.x += v.x; acc.y += v.y;
        }
    }
    float s = dinv[node];
    float2 b = *(const float2*)&bias[2 * lane];
    float vx = fmaxf(acc.x * s + b.x, 0.f);   // feature 2*lane
    float vy = fmaxf(acc.y * s + b.y, 0.f);   // feature 2*lane+1
    // head: Wl[f][c] at Wl[f*2+c]; lane covers f0=2l (wl.x,wl.y), f1=2l+1 (wl.z,wl.w)
    float4 wl = *(const float4*)&Wl[4 * lane];
    float a0 = vx * wl.x + vy * wl.z;
    float a1 = vx * wl.y + vy * wl.w;
#pragma unroll
    for (int off = 32; off > 0; off >>= 1) {
        a0 += __shfl_xor(a0, off);
        a1 += __shfl_xor(a1, off);
    }
    if (lane == 0) {
        out[node * 2 + 0] = a0 + bl[0];
        out[node * 2 + 1] = a1 + bl[1];
    }
}

// ---------------- launch ----------------
extern "C" void kernel_launch(void* const* d_in, const int* in_sizes, int n_in,
                              void* d_out, int out_size, void* d_ws, size_t ws_size,
                              hipStream_t stream) {
    const float* x  = (const float*)d_in[0];
    const int*   ei = (const int*)d_in[1];
    const float* W1 = (const float*)d_in[2];
    const float* b1 = (const float*)d_in[3];
    const float* W2 = (const float*)d_in[4];
    const float* b2 = (const float*)d_in[5];
    const float* Wl = (const float*)d_in[6];
    const float* bl = (const float*)d_in[7];
    float* out = (float*)d_out;

    int n = in_sizes[0] / FIN;          // 200000
    int E = in_sizes[1] / 2;            // 3200000
    const int* srcp = ei;
    const int* dstp = ei + E;

    char* w = (char*)d_ws;
    auto alloc = [&](size_t bytes) {
        char* p = w;
        w += (bytes + 255) & ~(size_t)255;
        return (void*)p;
    };
    int*   deg     = (int*)  alloc((size_t)n * 4);
    int*   fillptr = (int*)  alloc((size_t)n * 4);
    int*   rowptr  = (int*)  alloc(((size_t)n + 1) * 4);
    int    nb      = (n + SCHUNK - 1) / SCHUNK;
    int*   partial = (int*)  alloc((size_t)nb * 4);
    float* dinv    = (float*)alloc((size_t)n * 4);
    int*   colv    = (int*)  alloc((size_t)E * 4);
    float* hbuf    = (float*)alloc((size_t)n * HID * 4);
    float* ybuf    = (float*)alloc((size_t)n * HID * 4);

    hipMemsetAsync(deg, 0, (size_t)n * 4, stream);

    count_deg<<<(E + 255) / 256, 256, 0, stream>>>(dstp, deg, E, n);
    dinv_k<<<(n + 255) / 256, 256, 0, stream>>>(deg, dinv, n);
    scan_partial<<<nb, 256, 0, stream>>>(deg, partial, n);
    scan_level2<<<1, 256, 0, stream>>>(partial, nb, rowptr, n);
    scan_write<<<nb, 256, 0, stream>>>(deg, partial, rowptr, n);
    copy_cursor<<<(n + 255) / 256, 256, 0, stream>>>(rowptr, fillptr, n);
    fill_csr<<<(E + 255) / 256, 256, 0, stream>>>(srcp, dstp, fillptr, colv, E, n);

    // layer 1: hs1 = (x@W1)*dinv ; y1 = relu(dinv*(hs1 + gather) + b1)
    gemm_scale<<<(n + BM - 1) / BM, 256, 0, stream>>>(x, W1, dinv, hbuf, n, FIN);
    agg_relu<<<(n + 3) / 4, 256, 0, stream>>>(hbuf, rowptr, colv, dinv, b1, ybuf, n);

    // layer 2 GEMM
    gemm_scale<<<(n + BM - 1) / BM, 256, 0, stream>>>(ybuf, W2, dinv, hbuf, n, HID);

    // fused layer-2 aggregation + relu + head
    agg_relu_head<<<(n + 3) / 4, 256, 0, stream>>>(hbuf, rowptr, colv, dinv, b2,
                                                   Wl, bl, out, n);
}

// Round 3
// 1154.617 us; speedup vs baseline: 1.4680x; 1.4680x over previous
//
#include <hip/hip_runtime.h>
#include <hip/hip_bf16.h>

// ---------------- problem constants ----------------
#define FIN 165
#define HID 128
#define SCHUNK 2048    // scan chunk (256 thr * 8)

typedef __attribute__((ext_vector_type(8))) short short8;   // 8 bf16 (4 VGPRs)
typedef __attribute__((ext_vector_type(4))) float float4v;  // 4 fp32 acc

// round-to-nearest-even fp32 -> bf16 split: v ~= hi + lo, residual ~ 2^-18 |v|
__device__ inline void bf16split(float v, short& h, short& l) {
    unsigned u = __float_as_uint(v);
    unsigned r = u + 0x7fffu + ((u >> 16) & 1u);
    h = (short)(r >> 16);
    float hf = __uint_as_float(((unsigned)(unsigned short)h) << 16);
    float lf = v - hf;                       // exact in fp32
    unsigned u2 = __float_as_uint(lf);
    unsigned r2 = u2 + 0x7fffu + ((u2 >> 16) & 1u);
    l = (short)(r2 >> 16);
}

// ---------------- CSR build ----------------
__global__ __launch_bounds__(256) void count_deg(const int* __restrict__ dst,
                                                 int* __restrict__ deg, int E, int n) {
    int e = blockIdx.x * 256 + threadIdx.x;
    if (e < E) {
        int d = dst[e];
        if ((unsigned)d < (unsigned)n) atomicAdd(&deg[d], 1);
    }
}

__global__ __launch_bounds__(256) void dinv_k(const int* __restrict__ deg,
                                              float* __restrict__ dinv, int n) {
    int i = blockIdx.x * 256 + threadIdx.x;
    if (i < n) dinv[i] = rsqrtf((float)(deg[i] + 1));   // +1 self loop
}

__global__ __launch_bounds__(256) void scan_partial(const int* __restrict__ deg,
                                                    int* __restrict__ partial, int n) {
    __shared__ int sm[256];
    int base = blockIdx.x * SCHUNK;
    int s = 0;
    for (int i = threadIdx.x; i < SCHUNK; i += 256) {
        int idx = base + i;
        s += (idx < n) ? deg[idx] : 0;
    }
    sm[threadIdx.x] = s;
    __syncthreads();
    for (int off = 128; off > 0; off >>= 1) {
        if (threadIdx.x < off) sm[threadIdx.x] += sm[threadIdx.x + off];
        __syncthreads();
    }
    if (threadIdx.x == 0) partial[blockIdx.x] = sm[0];
}

__global__ __launch_bounds__(256) void scan_level2(int* __restrict__ partial, int nb,
                                                   int* __restrict__ rowptr, int n) {
    __shared__ int sm[256];
    int t = threadIdx.x;
    int v = (t < nb) ? partial[t] : 0;
    sm[t] = v;
    __syncthreads();
    for (int off = 1; off < 256; off <<= 1) {
        int u = (t >= off) ? sm[t - off] : 0;
        __syncthreads();
        sm[t] += u;
        __syncthreads();
    }
    if (t < nb) partial[t] = sm[t] - v;      // exclusive
    if (t == 0) rowptr[n] = sm[255];         // total == E
}

__global__ __launch_bounds__(256) void scan_write(const int* __restrict__ deg,
                                                  const int* __restrict__ partial,
                                                  int* __restrict__ rowptr, int n) {
    __shared__ int sm[256];
    int base = blockIdx.x * SCHUNK;
    int vals[8];
    int s = 0;
#pragma unroll
    for (int q = 0; q < 8; ++q) {
        int idx = base + threadIdx.x * 8 + q;
        vals[q] = (idx < n) ? deg[idx] : 0;
        s += vals[q];
    }
    sm[threadIdx.x] = s;
    __syncthreads();
    for (int off = 1; off < 256; off <<= 1) {
        int u = (threadIdx.x >= off) ? sm[threadIdx.x - off] : 0;
        __syncthreads();
        sm[threadIdx.x] += u;
        __syncthreads();
    }
    int excl = partial[blockIdx.x] + (threadIdx.x > 0 ? sm[threadIdx.x - 1] : 0);
#pragma unroll
    for (int q = 0; q < 8; ++q) {
        int idx = base + threadIdx.x * 8 + q;
        if (idx < n) rowptr[idx] = excl;
        excl += vals[q];
    }
}

__global__ __launch_bounds__(256) void copy_cursor(const int* __restrict__ rowptr,
                                                   int* __restrict__ fillptr, int n) {
    int i = blockIdx.x * 256 + threadIdx.x;
    if (i < n) fillptr[i] = rowptr[i];
}

__global__ __launch_bounds__(256) void fill_csr(const int* __restrict__ src,
                                                const int* __restrict__ dst,
                                                int* __restrict__ fillptr,
                                                int* __restrict__ col, int E, int n) {
    int e = blockIdx.x * 256 + threadIdx.x;
    if (e < E) {
        int d = dst[e];
        int s = src[e];
        if ((unsigned)d < (unsigned)n && (unsigned)s < (unsigned)n) {
            int pos = atomicAdd(&fillptr[d], 1);
            col[pos] = s;
        }
    }
}

// ---------------- W swizzle: fp32 [K x 128] -> bf16 hi/lo in MFMA B-frag order --------
// out layout: hi block [(ks*8+ct)*64 + lane] of short8, then lo block (k32*8*64 short8s).
// B-frag element j: k = ks*32 + (lane>>4)*8 + j, col = ct*16 + (lane&15). Zero-pad k>=K.
__global__ __launch_bounds__(256) void wswz(const float* __restrict__ W,
                                            short8* __restrict__ out, int K, int k32) {
    int idx = blockIdx.x * 256 + threadIdx.x;
    int tot = k32 * 8 * 64;
    if (idx >= tot) return;
    int lane = idx & 63;
    int ct = (idx >> 6) & 7;
    int ks = idx >> 9;
    int col = ct * 16 + (lane & 15);
    int kb = ks * 32 + (lane >> 4) * 8;
    short8 hi, lo;
#pragma unroll
    for (int j = 0; j < 8; ++j) {
        int k = kb + j;
        float v = (k < K) ? W[k * HID + col] : 0.f;
        short h, l;
        bf16split(v, h, l);
        hi[j] = h; lo[j] = l;
    }
    out[idx] = hi;
    out[tot + idx] = lo;
}

// ---------------- MFMA GEMM: H[r,c] = dinv[r] * sum_k X[r,k] W[k,c] ----------------
// 256 thr = 4 waves; block does 64 rows x 128 cols; wave does 16 rows x 128 cols.
// A-frags read directly from global X (fp32) and split to bf16 hi/lo in registers;
// B-frags read from pre-swizzled Wsw (L2-resident). No LDS, no barriers.
// Split-precision: acc += Ah*Bh + Al*Bh + Ah*Bl  (Al*Bl dropped, ~2^-18 rel).
// Requires n % 64 == 0 (200000 = 3125*64).
__global__ __launch_bounds__(256) void gemm_mfma(const float* __restrict__ X,
                                                 const short8* __restrict__ Wsw,
                                                 const float* __restrict__ dinv,
                                                 float* __restrict__ H,
                                                 int n, int K, int kfull, int k32) {
    int wave = threadIdx.x >> 6, lane = threadIdx.x & 63;
    int r0 = blockIdx.x * 64 + wave * 16;
    int m = lane & 15, kph = lane >> 4;
    int row = r0 + m;
    const float* xrow = X + (size_t)row * K + kph * 8;
    const short8* Whi = Wsw;
    const short8* Wlo = Wsw + (size_t)k32 * 8 * 64;

    float4v acc[8];
#pragma unroll
    for (int ct = 0; ct < 8; ++ct) acc[ct] = (float4v){0.f, 0.f, 0.f, 0.f};

    for (int ks = 0; ks < kfull; ++ks) {
        float xv[8];
#pragma unroll
        for (int j = 0; j < 8; ++j) xv[j] = xrow[ks * 32 + j];
        short8 ah, al;
#pragma unroll
        for (int j = 0; j < 8; ++j) {
            short h, l; bf16split(xv[j], h, l);
            ah[j] = h; al[j] = l;
        }
#pragma unroll
        for (int ct = 0; ct < 8; ++ct) {
            short8 bh = Whi[(ks * 8 + ct) * 64 + lane];
            short8 bl = Wlo[(ks * 8 + ct) * 64 + lane];
            acc[ct] = __builtin_amdgcn_mfma_f32_16x16x32_bf16(ah, bh, acc[ct], 0, 0, 0);
            acc[ct] = __builtin_amdgcn_mfma_f32_16x16x32_bf16(al, bh, acc[ct], 0, 0, 0);
            acc[ct] = __builtin_amdgcn_mfma_f32_16x16x32_bf16(ah, bl, acc[ct], 0, 0, 0);
        }
    }
    if (kfull < k32) {                       // K-tail (layer 1: k = 160..164)
        int ks = kfull;
        int kb = ks * 32 + kph * 8;
        float xv[8];
#pragma unroll
        for (int j = 0; j < 8; ++j) xv[j] = (kb + j < K) ? xrow[ks * 32 + j] : 0.f;
        short8 ah, al;
#pragma unroll
        for (int j = 0; j < 8; ++j) {
            short h, l; bf16split(xv[j], h, l);
            ah[j] = h; al[j] = l;
        }
#pragma unroll
        for (int ct = 0; ct < 8; ++ct) {
            short8 bh = Whi[(ks * 8 + ct) * 64 + lane];
            short8 bl = Wlo[(ks * 8 + ct) * 64 + lane];
            acc[ct] = __builtin_amdgcn_mfma_f32_16x16x32_bf16(ah, bh, acc[ct], 0, 0, 0);
            acc[ct] = __builtin_amdgcn_mfma_f32_16x16x32_bf16(al, bh, acc[ct], 0, 0, 0);
            acc[ct] = __builtin_amdgcn_mfma_f32_16x16x32_bf16(ah, bl, acc[ct], 0, 0, 0);
        }
    }
    // epilogue: C/D layout col=lane&15, row=(lane>>4)*4+reg  [m89-verified]
    int ccol = lane & 15, crow = (lane >> 4) * 4;
#pragma unroll
    for (int r = 0; r < 4; ++r) {
        int gr = r0 + crow + r;
        float s = dinv[gr];
#pragma unroll
        for (int ct = 0; ct < 8; ++ct)
            H[(size_t)gr * HID + ct * 16 + ccol] = acc[ct][r] * s;
    }
}

// ---------------- aggregation: one wave per node, float2 per lane ----------------
// Y[i,f] = relu(dinv[i]*(HS[i,f] + sum_nbr HS[s,f]) + b[f])
__global__ __launch_bounds__(256) void agg_relu(const float* __restrict__ HS,
                                                const int* __restrict__ rowptr,
                                                const int* __restrict__ col,
                                                const float* __restrict__ dinv,
                                                const float* __restrict__ bias,
                                                float* __restrict__ Y, int n) {
    int node = blockIdx.x * 4 + (threadIdx.x >> 6);
    int lane = threadIdx.x & 63;
    if (node >= n) return;
    int start = rowptr[node], end = rowptr[node + 1];
    float2 acc = *(const float2*)&HS[(long)node * HID + 2 * lane];   // self loop
    for (int j0 = start; j0 < end; j0 += 64) {
        int cnt = min(64, end - j0);
        int cv = (j0 + lane < end) ? col[j0 + lane] : 0;
        int t = 0;
        for (; t + 4 <= cnt; t += 4) {                 // 4 loads in flight
            int c0 = __shfl(cv, t), c1 = __shfl(cv, t + 1);
            int c2 = __shfl(cv, t + 2), c3 = __shfl(cv, t + 3);
            float2 v0 = *(const float2*)&HS[(long)c0 * HID + 2 * lane];
            float2 v1 = *(const float2*)&HS[(long)c1 * HID + 2 * lane];
            float2 v2 = *(const float2*)&HS[(long)c2 * HID + 2 * lane];
            float2 v3 = *(const float2*)&HS[(long)c3 * HID + 2 * lane];
            acc.x += v0.x; acc.y += v0.y;
            acc.x += v1.x; acc.y += v1.y;
            acc.x += v2.x; acc.y += v2.y;
            acc.x += v3.x; acc.y += v3.y;
        }
        for (; t < cnt; ++t) {
            int c = __shfl(cv, t);
            float2 v = *(const float2*)&HS[(long)c * HID + 2 * lane];
            acc.x += v.x; acc.y += v.y;
        }
    }
    float s = dinv[node];
    float2 b = *(const float2*)&bias[2 * lane];
    float2 o;
    o.x = fmaxf(acc.x * s + b.x, 0.f);
    o.y = fmaxf(acc.y * s + b.y, 0.f);
    *(float2*)&Y[(long)node * HID + 2 * lane] = o;
}

// ---------------- fused layer-2 aggregation + relu + head ----------------
__global__ __launch_bounds__(256) void agg_relu_head(const float* __restrict__ HS,
                                                     const int* __restrict__ rowptr,
                                                     const int* __restrict__ col,
                                                     const float* __restrict__ dinv,
                                                     const float* __restrict__ bias,
                                                     const float* __restrict__ Wl,
                                                     const float* __restrict__ bl,
                                                     float* __restrict__ out, int n) {
    int node = blockIdx.x * 4 + (threadIdx.x >> 6);
    int lane = threadIdx.x & 63;
    if (node >= n) return;
    int start = rowptr[node], end = rowptr[node + 1];
    float2 acc = *(const float2*)&HS[(long)node * HID + 2 * lane];   // self loop
    for (int j0 = start; j0 < end; j0 += 64) {
        int cnt = min(64, end - j0);
        int cv = (j0 + lane < end) ? col[j0 + lane] : 0;
        int t = 0;
        for (; t + 4 <= cnt; t += 4) {
            int c0 = __shfl(cv, t), c1 = __shfl(cv, t + 1);
            int c2 = __shfl(cv, t + 2), c3 = __shfl(cv, t + 3);
            float2 v0 = *(const float2*)&HS[(long)c0 * HID + 2 * lane];
            float2 v1 = *(const float2*)&HS[(long)c1 * HID + 2 * lane];
            float2 v2 = *(const float2*)&HS[(long)c2 * HID + 2 * lane];
            float2 v3 = *(const float2*)&HS[(long)c3 * HID + 2 * lane];
            acc.x += v0.x; acc.y += v0.y;
            acc.x += v1.x; acc.y += v1.y;
            acc.x += v2.x; acc.y += v2.y;
            acc.x += v3.x; acc.y += v3.y;
        }
        for (; t < cnt; ++t) {
            int c = __shfl(cv, t);
            float2 v = *(const float2*)&HS[(long)c * HID + 2 * lane];
            acc.x += v.x; acc.y += v.y;
        }
    }
    float s = dinv[node];
    float2 b = *(const float2*)&bias[2 * lane];
    float vx = fmaxf(acc.x * s + b.x, 0.f);   // feature 2*lane
    float vy = fmaxf(acc.y * s + b.y, 0.f);   // feature 2*lane+1
    float4 wl = *(const float4*)&Wl[4 * lane];
    float a0 = vx * wl.x + vy * wl.z;
    float a1 = vx * wl.y + vy * wl.w;
#pragma unroll
    for (int off = 32; off > 0; off >>= 1) {
        a0 += __shfl_xor(a0, off);
        a1 += __shfl_xor(a1, off);
    }
    if (lane == 0) {
        out[node * 2 + 0] = a0 + bl[0];
        out[node * 2 + 1] = a1 + bl[1];
    }
}

// ---------------- launch ----------------
extern "C" void kernel_launch(void* const* d_in, const int* in_sizes, int n_in,
                              void* d_out, int out_size, void* d_ws, size_t ws_size,
                              hipStream_t stream) {
    const float* x  = (const float*)d_in[0];
    const int*   ei = (const int*)d_in[1];
    const float* W1 = (const float*)d_in[2];
    const float* b1 = (const float*)d_in[3];
    const float* W2 = (const float*)d_in[4];
    const float* b2 = (const float*)d_in[5];
    const float* Wl = (const float*)d_in[6];
    const float* bl = (const float*)d_in[7];
    float* out = (float*)d_out;

    int n = in_sizes[0] / FIN;          // 200000
    int E = in_sizes[1] / 2;            // 3200000
    const int* srcp = ei;
    const int* dstp = ei + E;

    char* w = (char*)d_ws;
    auto alloc = [&](size_t bytes) {
        char* p = w;
        w += (bytes + 255) & ~(size_t)255;
        return (void*)p;
    };
    int*    deg     = (int*)   alloc((size_t)n * 4);
    int*    fillptr = (int*)   alloc((size_t)n * 4);
    int*    rowptr  = (int*)   alloc(((size_t)n + 1) * 4);
    int     nb      = (n + SCHUNK - 1) / SCHUNK;
    int*    partial = (int*)   alloc((size_t)nb * 4);
    float*  dinv    = (float*) alloc((size_t)n * 4);
    int*    colv    = (int*)   alloc((size_t)E * 4);
    float*  hbuf    = (float*) alloc((size_t)n * HID * 4);
    float*  ybuf    = (float*) alloc((size_t)n * HID * 4);
    const int K32_1 = (FIN + 31) / 32;  // 6
    const int K32_2 = HID / 32;         // 4
    short8* w1sw    = (short8*)alloc((size_t)2 * K32_1 * 8 * 64 * 16);
    short8* w2sw    = (short8*)alloc((size_t)2 * K32_2 * 8 * 64 * 16);

    hipMemsetAsync(deg, 0, (size_t)n * 4, stream);

    // W pre-swizzle (tiny, overlaps CSR build)
    wswz<<<(K32_1 * 8 * 64 + 255) / 256, 256, 0, stream>>>(W1, w1sw, FIN, K32_1);
    wswz<<<(K32_2 * 8 * 64 + 255) / 256, 256, 0, stream>>>(W2, w2sw, HID, K32_2);

    // CSR build
    count_deg<<<(E + 255) / 256, 256, 0, stream>>>(dstp, deg, E, n);
    dinv_k<<<(n + 255) / 256, 256, 0, stream>>>(deg, dinv, n);
    scan_partial<<<nb, 256, 0, stream>>>(deg, partial, n);
    scan_level2<<<1, 256, 0, stream>>>(partial, nb, rowptr, n);
    scan_write<<<nb, 256, 0, stream>>>(deg, partial, rowptr, n);
    copy_cursor<<<(n + 255) / 256, 256, 0, stream>>>(rowptr, fillptr, n);
    fill_csr<<<(E + 255) / 256, 256, 0, stream>>>(srcp, dstp, fillptr, colv, E, n);

    // layer 1: hs1 = (x@W1)*dinv ; y1 = relu(dinv*(hs1 + gather) + b1)
    gemm_mfma<<<n / 64, 256, 0, stream>>>(x, w1sw, dinv, hbuf, n, FIN, FIN / 32, K32_1);
    agg_relu<<<(n + 3) / 4, 256, 0, stream>>>(hbuf, rowptr, colv, dinv, b1, ybuf, n);

    // layer 2 GEMM
    gemm_mfma<<<n / 64, 256, 0, stream>>>(ybuf, w2sw, dinv, hbuf, n, HID, HID / 32, K32_2);

    // fused layer-2 aggregation + relu + head
    agg_relu_head<<<(n + 3) / 4, 256, 0, stream>>>(hbuf, rowptr, colv, dinv, b2,
                                                   Wl, bl, out, n);
}